// Round 1
// baseline (139.594 us; speedup 1.0000x reference)
//
#include <hip/hip_runtime.h>

#define NBINS 10
#define NG 4
#define NCOPIES 16   // one histogram copy per 16-lane group (4 waves * 4 groups)
#define CSTRIDE 41   // 40 bins padded +1 to decorrelate banks across copies

__global__ void __launch_bounds__(64) wb_zero(float* counts) {
    int t = threadIdx.x;
    if (t < NG * NBINS) counts[t] = 0.0f;
}

__global__ void __launch_bounds__(256) wb_hist(const float4* __restrict__ acts,
                                               const int4* __restrict__ labels,
                                               float* __restrict__ counts, int n4) {
    __shared__ float lh[NCOPIES * CSTRIDE];
    for (int i = threadIdx.x; i < NCOPIES * CSTRIDE; i += 256) lh[i] = 0.0f;
    __syncthreads();

    float* myh = &lh[(threadIdx.x >> 4) * CSTRIDE];
    const int stride = gridDim.x * 256;
    for (int idx = blockIdx.x * 256 + threadIdx.x; idx < n4; idx += stride) {
        float4 a = acts[idx];
        int4  g = labels[idx];
        const float xv[4] = {a.x, a.y, a.z, a.w};
        const int   gv[4] = {g.x, g.y, g.z, g.w};
        #pragma unroll
        for (int e = 0; e < 4; ++e) {
            // c = sigmoid(x) - 1e-4, in (-1e-4, 1-1e-4)
            float c = 1.0f / (1.0f + __expf(-xv[e])) - 0.0001f;
            int j0 = (int)floorf(c * 10.0f);      // -1..9
            int base = gv[e] * NBINS;
            // exact triangular-kernel weights for the two candidate bins
            float w0 = 0.1f - fabsf(c - 0.1f * (float)j0);
            float w1 = 0.1f - fabsf(c - 0.1f * (float)(j0 + 1));
            if (j0 >= 0 && j0 <= NBINS - 1 && w0 > 0.0f)
                atomicAdd(&myh[base + j0], w0);
            if (j0 + 1 >= 0 && j0 + 1 <= NBINS - 1 && w1 > 0.0f)
                atomicAdd(&myh[base + j0 + 1], w1);
        }
    }
    __syncthreads();

    for (int t = threadIdx.x; t < NG * NBINS; t += 256) {
        float s = 0.0f;
        #pragma unroll
        for (int k = 0; k < NCOPIES; ++k) s += lh[k * CSTRIDE + t];
        atomicAdd(&counts[t], s);
    }
}

__global__ void __launch_bounds__(64) wb_final(const float* __restrict__ counts,
                                               const float* __restrict__ bary,
                                               float* __restrict__ out) {
    if (threadIdx.x < NBINS) out[1 + threadIdx.x] = bary[threadIdx.x];
    if (threadIdx.x != 0) return;

    float cdf_b[NBINS];
    float acc = 0.0f;
    for (int j = 0; j < NBINS; ++j) { acc += bary[j]; cdf_b[j] = acc; }

    float total = 0.0f;
    for (int gI = 0; gI < NG; ++gI) {
        float h[NBINS];
        float s = 0.0f;
        for (int j = 0; j < NBINS; ++j) { h[j] = counts[gI * NBINS + j] + 0.0001f; s += h[j]; }
        for (int j = 0; j < NBINS; ++j) h[j] /= s;
        float s2 = 0.0f;                       // genHists renorm (fp no-op, kept for fidelity)
        for (int j = 0; j < NBINS; ++j) s2 += h[j];
        for (int j = 0; j < NBINS; ++j) h[j] /= s2;

        float cdf_a[NBINS];
        acc = 0.0f;
        for (int j = 0; j < NBINS; ++j) { acc += h[j]; cdf_a[j] = acc; }

        // qs = sort(concat(cdf_a, cdf_b)) : merge of two sorted arrays
        float qs[2 * NBINS];
        int ia = 0, ib = 0;
        for (int k = 0; k < 2 * NBINS; ++k) {
            float va = (ia < NBINS) ? cdf_a[ia] : 3.4e38f;
            float vb = (ib < NBINS) ? cdf_b[ib] : 3.4e38f;
            if (va <= vb) { qs[k] = va; ++ia; } else { qs[k] = vb; ++ib; }
        }

        float prev = 0.0f, lg = 0.0f;
        for (int k = 0; k < 2 * NBINS; ++k) {
            float q = qs[k];
            int sa = 0; while (sa < NBINS && cdf_a[sa] < q) ++sa;  // searchsorted left
            int sb = 0; while (sb < NBINS && cdf_b[sb] < q) ++sb;
            if (sa > NBINS - 1) sa = NBINS - 1;
            if (sb > NBINS - 1) sb = NBINS - 1;
            float d = q - prev; prev = q;
            float diff = (float)(sa - sb);     // xs = 0..n-1, so quantile value == index
            lg += d * diff * diff;
        }
        total += lg;
    }
    out[0] = total;
}

extern "C" void kernel_launch(void* const* d_in, const int* in_sizes, int n_in,
                              void* d_out, int out_size, void* d_ws, size_t ws_size,
                              hipStream_t stream) {
    const float* acts   = (const float*)d_in[0];
    const float* bary   = (const float*)d_in[1];
    const int*   labels = (const int*)d_in[2];
    float* outp   = (float*)d_out;
    float* counts = (float*)d_ws;          // 40 floats
    int N  = in_sizes[0];
    int n4 = N >> 2;                       // N = 8388608, divisible by 4

    wb_zero<<<1, 64, 0, stream>>>(counts);
    wb_hist<<<2048, 256, 0, stream>>>((const float4*)acts, (const int4*)labels, counts, n4);
    wb_final<<<1, 64, 0, stream>>>(counts, bary, outp);
}

// Round 2
// 123.267 us; speedup vs baseline: 1.1325x; 1.1325x over previous
//
#include <hip/hip_runtime.h>

#define NBINS 10
#define NG 4
#define NH (NG * NBINS)      // 40
#define NCOPIES 16           // one LDS hist copy per 16-lane group
#define CSTRIDE 41           // 40 + 1 pad to decorrelate banks across copies

__device__ __forceinline__ void proc4(float4 a, int4 g, float* myh) {
    const float xv[4] = {a.x, a.y, a.z, a.w};
    const int   gv[4] = {g.x, g.y, g.z, g.w};
    #pragma unroll
    for (int e = 0; e < 4; ++e) {
        float c = 1.0f / (1.0f + __expf(-xv[e])) - 0.0001f;   // (-1e-4, 1-1e-4)
        int j0 = (int)floorf(c * 10.0f);                       // -1..9
        int base = gv[e] * NBINS;
        float w0 = 0.1f - fabsf(c - 0.1f * (float)j0);
        float w1 = 0.1f - fabsf(c - 0.1f * (float)(j0 + 1));
        if (j0 >= 0 && w0 > 0.0f)          atomicAdd(&myh[base + j0], w0);
        if (j0 < NBINS - 1 && w1 > 0.0f)   atomicAdd(&myh[base + j0 + 1], w1);
    }
}

__global__ void __launch_bounds__(256) wb_hist(const float4* __restrict__ acts,
                                               const int4* __restrict__ labels,
                                               const float* __restrict__ acts_s,
                                               const int* __restrict__ labels_s,
                                               float* __restrict__ parts,
                                               int n4, int n, int nparts) {
    __shared__ float lh[NCOPIES * CSTRIDE];
    for (int i = threadIdx.x; i < NCOPIES * CSTRIDE; i += 256) lh[i] = 0.0f;
    __syncthreads();

    float* myh = &lh[(threadIdx.x >> 4) * CSTRIDE];
    const int gsz = gridDim.x * 256;
    int idx = blockIdx.x * 256 + threadIdx.x;
    // batched main loop: 8 loads (128B/lane) in flight before processing
    for (; idx + 3 * gsz < n4; idx += 4 * gsz) {
        float4 a0 = acts[idx];
        float4 a1 = acts[idx + gsz];
        float4 a2 = acts[idx + 2 * gsz];
        float4 a3 = acts[idx + 3 * gsz];
        int4 g0 = labels[idx];
        int4 g1 = labels[idx + gsz];
        int4 g2 = labels[idx + 2 * gsz];
        int4 g3 = labels[idx + 3 * gsz];
        proc4(a0, g0, myh); proc4(a1, g1, myh);
        proc4(a2, g2, myh); proc4(a3, g3, myh);
    }
    for (; idx < n4; idx += gsz) proc4(acts[idx], labels[idx], myh);

    // scalar tail for N % 4 != 0 (not hit for N = 8388608)
    if (blockIdx.x == 0 && threadIdx.x == 0) {
        for (int i = n4 * 4; i < n; ++i) {
            float c = 1.0f / (1.0f + __expf(-acts_s[i])) - 0.0001f;
            int j0 = (int)floorf(c * 10.0f);
            int base = labels_s[i] * NBINS;
            float w0 = 0.1f - fabsf(c - 0.1f * (float)j0);
            float w1 = 0.1f - fabsf(c - 0.1f * (float)(j0 + 1));
            if (j0 >= 0 && w0 > 0.0f)        atomicAdd(&myh[base + j0], w0);
            if (j0 < NBINS - 1 && w1 > 0.0f) atomicAdd(&myh[base + j0 + 1], w1);
        }
    }
    __syncthreads();

    // per-block partials, bin-major: parts[j][block] — unique addresses, no atomics
    for (int t = threadIdx.x; t < NH; t += 256) {
        float s = 0.0f;
        #pragma unroll
        for (int k = 0; k < NCOPIES; ++k) s += lh[k * CSTRIDE + t];
        parts[t * nparts + blockIdx.x] = s;
    }
}

__global__ void __launch_bounds__(1024) wb_final(const float* __restrict__ parts,
                                                 const float* __restrict__ bary,
                                                 float* __restrict__ out, int nparts) {
    __shared__ float hist[NH];
    __shared__ float bsh[NBINS];
    __shared__ float losses[NG];

    if (threadIdx.x < NBINS) {
        float b = bary[threadIdx.x];
        bsh[threadIdx.x] = b;
        out[1 + threadIdx.x] = b;     // tuple output: bary_est passthrough
    }

    // coalesced reduce of [40][nparts] partials: wave w handles bins w, w+16, ...
    int wave = threadIdx.x >> 6, lane = threadIdx.x & 63;
    for (int j = wave; j < NH; j += 16) {
        float s = 0.0f;
        for (int i = lane; i < nparts; i += 64) s += parts[j * nparts + i];
        #pragma unroll
        for (int off = 32; off; off >>= 1) s += __shfl_down(s, off);
        if (lane == 0) hist[j] = s;
    }
    __syncthreads();

    // 4 lanes (one per group), uniform control flow, all arrays register-resident
    if (threadIdx.x < NG) {
        const int gI = threadIdx.x;
        float h[NBINS];
        float s = 0.0f;
        #pragma unroll
        for (int j = 0; j < NBINS; ++j) { h[j] = hist[gI * NBINS + j] + 0.0001f; s += h[j]; }
        #pragma unroll
        for (int j = 0; j < NBINS; ++j) h[j] /= s;
        float s2 = 0.0f;                    // genHists renorm (fp no-op, kept for fidelity)
        #pragma unroll
        for (int j = 0; j < NBINS; ++j) s2 += h[j];
        #pragma unroll
        for (int j = 0; j < NBINS; ++j) h[j] /= s2;

        float cdfa[NBINS], cdfb[NBINS];
        float acc = 0.0f;
        #pragma unroll
        for (int j = 0; j < NBINS; ++j) { acc += h[j]; cdfa[j] = acc; }
        acc = 0.0f;
        #pragma unroll
        for (int j = 0; j < NBINS; ++j) { acc += bsh[j]; cdfb[j] = acc; }
        // top-equalization reproduces searchsorted clip at q > min(top_a, top_b)
        float T = fmaxf(cdfa[NBINS - 1], cdfb[NBINS - 1]);
        cdfa[NBINS - 1] = T;
        cdfb[NBINS - 1] = T;

        // sum over merged quantile intervals == sum of pairwise interval overlaps
        float loss = 0.0f, lo_a = 0.0f;
        #pragma unroll
        for (int i = 0; i < NBINS; ++i) {
            float hi_a = cdfa[i];
            float lo_b = 0.0f;
            #pragma unroll
            for (int j = 0; j < NBINS; ++j) {
                float hi_b = cdfb[j];
                float ov = fminf(hi_a, hi_b) - fmaxf(lo_a, lo_b);
                float w = (float)((i - j) * (i - j));
                loss += fmaxf(ov, 0.0f) * w;
                lo_b = hi_b;
            }
            lo_a = hi_a;
        }
        losses[gI] = loss;
    }
    __syncthreads();
    if (threadIdx.x == 0)
        out[0] = losses[0] + losses[1] + losses[2] + losses[3];
}

extern "C" void kernel_launch(void* const* d_in, const int* in_sizes, int n_in,
                              void* d_out, int out_size, void* d_ws, size_t ws_size,
                              hipStream_t stream) {
    const float* acts   = (const float*)d_in[0];
    const float* bary   = (const float*)d_in[1];
    const int*   labels = (const int*)d_in[2];
    float* outp  = (float*)d_out;
    float* parts = (float*)d_ws;
    int N  = in_sizes[0];
    int n4 = N >> 2;

    int nparts = 2048;
    while (nparts > 1 && (size_t)NH * nparts * sizeof(float) > ws_size) nparts >>= 1;

    wb_hist<<<nparts, 256, 0, stream>>>((const float4*)acts, (const int4*)labels,
                                        acts, labels, parts, n4, N, nparts);
    wb_final<<<1, 1024, 0, stream>>>(parts, bary, outp, nparts);
}

// Round 3
// 55.838 us; speedup vs baseline: 2.5000x; 2.2076x over previous
//
#include <hip/hip_runtime.h>

#define NBINS 10
#define NG 4
#define NH (NG * NBINS)      // 40
#define TPB 128              // 2 waves; each thread owns a private LDS column
#define DUMP NH              // dump row for out-of-range bins
#define NROWS (NH + 1)       // 41

// Per-sample update: two plain LDS read-modify-writes into the thread's
// private column (no atomics). addr = row*TPB + tid -> bank = tid%32,
// 2 lanes/bank per wave = conflict-free.
__device__ __forceinline__ void proc4(float4 a, int4 g, float* col) {
    const float xv[4] = {a.x, a.y, a.z, a.w};
    const int   gv[4] = {g.x, g.y, g.z, g.w};
    #pragma unroll
    for (int e = 0; e < 4; ++e) {
        float c = 1.0f / (1.0f + __expf(-xv[e])) - 0.0001f;   // (-1e-4, 1-1e-4)
        float fj = floorf(c * 10.0f);
        int j0 = (int)fj;                                      // -1..9
        int b = gv[e] * NBINS;
        float w0 = 0.1f - fabsf(c - 0.1f * fj);                // >= 0 always
        float w1 = 0.1f - fabsf(c - 0.1f * (fj + 1.0f));       // >= 0 always
        int r0 = (j0 >= 0) ? (b + j0) : DUMP;
        int r1 = (j0 <= NBINS - 2) ? (b + j0 + 1) : DUMP;
        col[r0 * TPB] += w0;
        col[r1 * TPB] += w1;
    }
}

__global__ void __launch_bounds__(TPB) wb_hist(const float4* __restrict__ acts,
                                               const int4* __restrict__ labels,
                                               const float* __restrict__ acts_s,
                                               const int* __restrict__ labels_s,
                                               float* __restrict__ parts,
                                               int n4, int n, int nparts) {
    __shared__ float lh[NROWS * TPB];
    const int tid = threadIdx.x;
    for (int i = tid; i < NROWS * TPB; i += TPB) lh[i] = 0.0f;
    __syncthreads();

    float* col = &lh[tid];
    const int gsz = gridDim.x * TPB;
    int idx = blockIdx.x * TPB + tid;
    // 8 loads (128B/lane) in flight per iteration
    for (; idx + 3 * gsz < n4; idx += 4 * gsz) {
        float4 a0 = acts[idx];
        float4 a1 = acts[idx + gsz];
        float4 a2 = acts[idx + 2 * gsz];
        float4 a3 = acts[idx + 3 * gsz];
        int4 g0 = labels[idx];
        int4 g1 = labels[idx + gsz];
        int4 g2 = labels[idx + 2 * gsz];
        int4 g3 = labels[idx + 3 * gsz];
        proc4(a0, g0, col); proc4(a1, g1, col);
        proc4(a2, g2, col); proc4(a3, g3, col);
    }
    for (; idx < n4; idx += gsz) proc4(acts[idx], labels[idx], col);

    // scalar tail for N % 4 != 0 (not hit for N = 8388608)
    if (blockIdx.x == 0 && tid == 0) {
        for (int i = n4 * 4; i < n; ++i) {
            float c = 1.0f / (1.0f + __expf(-acts_s[i])) - 0.0001f;
            float fj = floorf(c * 10.0f);
            int j0 = (int)fj;
            int b = labels_s[i] * NBINS;
            float w0 = 0.1f - fabsf(c - 0.1f * fj);
            float w1 = 0.1f - fabsf(c - 0.1f * (fj + 1.0f));
            int r0 = (j0 >= 0) ? (b + j0) : DUMP;
            int r1 = (j0 <= NBINS - 2) ? (b + j0 + 1) : DUMP;
            col[r0 * TPB] += w0;
            col[r1 * TPB] += w1;
        }
    }
    __syncthreads();

    // per-block partials: thread j sums row j with skewed start (<=2-way bank alias)
    if (tid < NH) {
        float s = 0.0f;
        for (int k = 0; k < TPB; ++k)
            s += lh[tid * TPB + ((tid + k) & (TPB - 1))];
        parts[tid * nparts + blockIdx.x] = s;
    }
}

__global__ void __launch_bounds__(1024) wb_final(const float* __restrict__ parts,
                                                 const float* __restrict__ bary,
                                                 float* __restrict__ out, int nparts) {
    __shared__ float hist[NH];
    __shared__ float bsh[NBINS];
    __shared__ float losses[NG];

    if (threadIdx.x < NBINS) {
        float b = bary[threadIdx.x];
        bsh[threadIdx.x] = b;
        out[1 + threadIdx.x] = b;     // tuple output: bary_est passthrough
    }

    // coalesced reduce of [40][nparts] partials: wave w handles bins w, w+16, ...
    int wave = threadIdx.x >> 6, lane = threadIdx.x & 63;
    for (int j = wave; j < NH; j += 16) {
        float s = 0.0f;
        for (int i = lane; i < nparts; i += 64) s += parts[j * nparts + i];
        #pragma unroll
        for (int off = 32; off; off >>= 1) s += __shfl_down(s, off);
        if (lane == 0) hist[j] = s;
    }
    __syncthreads();

    // 4 lanes (one per group), uniform control flow, all arrays register-resident
    if (threadIdx.x < NG) {
        const int gI = threadIdx.x;
        float h[NBINS];
        float s = 0.0f;
        #pragma unroll
        for (int j = 0; j < NBINS; ++j) { h[j] = hist[gI * NBINS + j] + 0.0001f; s += h[j]; }
        #pragma unroll
        for (int j = 0; j < NBINS; ++j) h[j] /= s;
        float s2 = 0.0f;                    // genHists renorm (fp no-op, kept for fidelity)
        #pragma unroll
        for (int j = 0; j < NBINS; ++j) s2 += h[j];
        #pragma unroll
        for (int j = 0; j < NBINS; ++j) h[j] /= s2;

        float cdfa[NBINS], cdfb[NBINS];
        float acc = 0.0f;
        #pragma unroll
        for (int j = 0; j < NBINS; ++j) { acc += h[j]; cdfa[j] = acc; }
        acc = 0.0f;
        #pragma unroll
        for (int j = 0; j < NBINS; ++j) { acc += bsh[j]; cdfb[j] = acc; }
        // top-equalization reproduces searchsorted clip at q > min(top_a, top_b)
        float T = fmaxf(cdfa[NBINS - 1], cdfb[NBINS - 1]);
        cdfa[NBINS - 1] = T;
        cdfb[NBINS - 1] = T;

        // sum over merged quantile intervals == sum of pairwise interval overlaps
        float loss = 0.0f, lo_a = 0.0f;
        #pragma unroll
        for (int i = 0; i < NBINS; ++i) {
            float hi_a = cdfa[i];
            float lo_b = 0.0f;
            #pragma unroll
            for (int j = 0; j < NBINS; ++j) {
                float hi_b = cdfb[j];
                float ov = fminf(hi_a, hi_b) - fmaxf(lo_a, lo_b);
                float w = (float)((i - j) * (i - j));
                loss += fmaxf(ov, 0.0f) * w;
                lo_b = hi_b;
            }
            lo_a = hi_a;
        }
        losses[gI] = loss;
    }
    __syncthreads();
    if (threadIdx.x == 0)
        out[0] = losses[0] + losses[1] + losses[2] + losses[3];
}

extern "C" void kernel_launch(void* const* d_in, const int* in_sizes, int n_in,
                              void* d_out, int out_size, void* d_ws, size_t ws_size,
                              hipStream_t stream) {
    const float* acts   = (const float*)d_in[0];
    const float* bary   = (const float*)d_in[1];
    const int*   labels = (const int*)d_in[2];
    float* outp  = (float*)d_out;
    float* parts = (float*)d_ws;
    int N  = in_sizes[0];
    int n4 = N >> 2;

    int nparts = 2048;
    while (nparts > 1 && (size_t)NH * nparts * sizeof(float) > ws_size) nparts >>= 1;

    wb_hist<<<nparts, TPB, 0, stream>>>((const float4*)acts, (const int4*)labels,
                                        acts, labels, parts, n4, N, nparts);
    wb_final<<<1, 1024, 0, stream>>>(parts, bary, outp, nparts);
}

// Round 4
// 33.034 us; speedup vs baseline: 4.2258x; 1.6903x over previous
//
#include <hip/hip_runtime.h>

#define NBINS 10
#define NG 4
#define NH (NG * NBINS)      // 40
#define TPB 128              // 2 waves; each thread owns a private LDS column
#define NROWS NH             // 40 rows -> 20 KB LDS -> exactly 8 blocks/CU

// Per-sample update: two plain LDS read-modify-writes into the thread's
// private column (no atomics, no divergence). addr = row*TPB + tid ->
// bank = tid%32, 2 lanes/bank per wave = conflict-free (free per m136).
// Triangular kernel with pitch == radius: w0 + w1 == r exactly, so
// t = c - 0.1*j0 gives w0 = 0.1 - t (bin j0), w1 = t (bin j0+1).
// Range edges handled by zeroing the weight and clamping the row.
__device__ __forceinline__ void proc4(float4 a, int4 g, float* col) {
    const float xv[4] = {a.x, a.y, a.z, a.w};
    const int   gv[4] = {g.x, g.y, g.z, g.w};
    #pragma unroll
    for (int e = 0; e < 4; ++e) {
        float ex = __expf(-xv[e]);
        float c = __builtin_amdgcn_rcpf(1.0f + ex) - 0.0001f;  // sigmoid - 1e-4
        float fj = floorf(c * 10.0f);
        int j0 = (int)fj;                                       // -1..9
        int b = gv[e] * NBINS;
        float t = c - 0.1f * fj;                                // in [0, 0.1)
        float w0 = 0.1f - t;
        float w1 = t;
        if (j0 < 0) w0 = 0.0f;          // cndmask; j0=-1 ~impossible for N(0,1)
        if (j0 > NBINS - 2) w1 = 0.0f;  // cndmask; j0=9 -> only w0 lands
        int r0 = b + max(j0, 0);
        int r1 = b + min(j0 + 1, NBINS - 1);
        col[r0 * TPB] += w0;
        col[r1 * TPB] += w1;
    }
}

__global__ void __launch_bounds__(TPB) wb_hist(const float4* __restrict__ acts,
                                               const int4* __restrict__ labels,
                                               const float* __restrict__ acts_s,
                                               const int* __restrict__ labels_s,
                                               float* __restrict__ parts,
                                               int n4, int n, int nparts) {
    __shared__ float lh[NROWS * TPB];
    const int tid = threadIdx.x;
    for (int i = tid; i < NROWS * TPB; i += TPB) lh[i] = 0.0f;
    __syncthreads();

    float* col = &lh[tid];
    const int gsz = gridDim.x * TPB;
    int idx = blockIdx.x * TPB + tid;
    // 8 loads (128B/lane) in flight per iteration
    for (; idx + 3 * gsz < n4; idx += 4 * gsz) {
        float4 a0 = acts[idx];
        float4 a1 = acts[idx + gsz];
        float4 a2 = acts[idx + 2 * gsz];
        float4 a3 = acts[idx + 3 * gsz];
        int4 g0 = labels[idx];
        int4 g1 = labels[idx + gsz];
        int4 g2 = labels[idx + 2 * gsz];
        int4 g3 = labels[idx + 3 * gsz];
        proc4(a0, g0, col); proc4(a1, g1, col);
        proc4(a2, g2, col); proc4(a3, g3, col);
    }
    for (; idx < n4; idx += gsz) proc4(acts[idx], labels[idx], col);

    // scalar tail for N % 4 != 0 (not hit for N = 8388608)
    if (blockIdx.x == 0 && tid == 0) {
        for (int i = n4 * 4; i < n; ++i) {
            float ex = __expf(-acts_s[i]);
            float c = __builtin_amdgcn_rcpf(1.0f + ex) - 0.0001f;
            float fj = floorf(c * 10.0f);
            int j0 = (int)fj;
            int b = labels_s[i] * NBINS;
            float t = c - 0.1f * fj;
            float w0 = 0.1f - t, w1 = t;
            if (j0 < 0) w0 = 0.0f;
            if (j0 > NBINS - 2) w1 = 0.0f;
            col[(b + max(j0, 0)) * TPB] += w0;
            col[(b + min(j0 + 1, NBINS - 1)) * TPB] += w1;
        }
    }
    __syncthreads();

    // per-block partials: thread j sums row j with skewed start (<=2-way alias)
    if (tid < NH) {
        float s = 0.0f;
        for (int k = 0; k < TPB; ++k)
            s += lh[tid * TPB + ((tid + k) & (TPB - 1))];
        parts[tid * nparts + blockIdx.x] = s;
    }
}

__global__ void __launch_bounds__(1024) wb_final(const float4* __restrict__ parts4,
                                                 const float* __restrict__ bary,
                                                 float* __restrict__ out, int nparts) {
    __shared__ float hist[NH];
    __shared__ float bsh[NBINS];
    __shared__ float losses[NG];

    if (threadIdx.x < NBINS) {
        float b = bary[threadIdx.x];
        bsh[threadIdx.x] = b;
        out[1 + threadIdx.x] = b;     // tuple output: bary_est passthrough
    }

    // float4 reduce of [40][nparts] partials: each float4 = 4 partials, same bin
    const int q4 = nparts >> 2;
    int wave = threadIdx.x >> 6, lane = threadIdx.x & 63;
    for (int j = wave; j < NH; j += 16) {
        float s = 0.0f;
        for (int i = lane; i < q4; i += 64) {
            float4 v = parts4[j * q4 + i];
            s += (v.x + v.y) + (v.z + v.w);
        }
        #pragma unroll
        for (int off = 32; off; off >>= 1) s += __shfl_down(s, off);
        if (lane == 0) hist[j] = s;
    }
    __syncthreads();

    // 4 lanes (one per group), uniform control flow, all arrays register-resident
    if (threadIdx.x < NG) {
        const int gI = threadIdx.x;
        float h[NBINS];
        float s = 0.0f;
        #pragma unroll
        for (int j = 0; j < NBINS; ++j) { h[j] = hist[gI * NBINS + j] + 0.0001f; s += h[j]; }
        #pragma unroll
        for (int j = 0; j < NBINS; ++j) h[j] /= s;
        float s2 = 0.0f;                    // genHists renorm (fp no-op, kept for fidelity)
        #pragma unroll
        for (int j = 0; j < NBINS; ++j) s2 += h[j];
        #pragma unroll
        for (int j = 0; j < NBINS; ++j) h[j] /= s2;

        float cdfa[NBINS], cdfb[NBINS];
        float acc = 0.0f;
        #pragma unroll
        for (int j = 0; j < NBINS; ++j) { acc += h[j]; cdfa[j] = acc; }
        acc = 0.0f;
        #pragma unroll
        for (int j = 0; j < NBINS; ++j) { acc += bsh[j]; cdfb[j] = acc; }
        // top-equalization reproduces searchsorted clip at q > min(top_a, top_b)
        float T = fmaxf(cdfa[NBINS - 1], cdfb[NBINS - 1]);
        cdfa[NBINS - 1] = T;
        cdfb[NBINS - 1] = T;

        // sum over merged quantile intervals == sum of pairwise interval overlaps
        float loss = 0.0f, lo_a = 0.0f;
        #pragma unroll
        for (int i = 0; i < NBINS; ++i) {
            float hi_a = cdfa[i];
            float lo_b = 0.0f;
            #pragma unroll
            for (int j = 0; j < NBINS; ++j) {
                float hi_b = cdfb[j];
                float ov = fminf(hi_a, hi_b) - fmaxf(lo_a, lo_b);
                float w = (float)((i - j) * (i - j));
                loss += fmaxf(ov, 0.0f) * w;
                lo_b = hi_b;
            }
            lo_a = hi_a;
        }
        losses[gI] = loss;
    }
    __syncthreads();
    if (threadIdx.x == 0)
        out[0] = losses[0] + losses[1] + losses[2] + losses[3];
}

extern "C" void kernel_launch(void* const* d_in, const int* in_sizes, int n_in,
                              void* d_out, int out_size, void* d_ws, size_t ws_size,
                              hipStream_t stream) {
    const float* acts   = (const float*)d_in[0];
    const float* bary   = (const float*)d_in[1];
    const int*   labels = (const int*)d_in[2];
    float* outp  = (float*)d_out;
    float* parts = (float*)d_ws;
    int N  = in_sizes[0];
    int n4 = N >> 2;

    int nparts = 2048;   // 8 blocks/CU * 256 CUs; 20 KB LDS -> exactly 8/CU
    while (nparts > 4 && (size_t)NH * nparts * sizeof(float) > ws_size) nparts >>= 1;

    wb_hist<<<nparts, TPB, 0, stream>>>((const float4*)acts, (const int4*)labels,
                                        acts, labels, parts, n4, N, nparts);
    wb_final<<<1, 1024, 0, stream>>>((const float4*)parts, bary, outp, nparts);
}